// Round 14
// baseline (226.524 us; speedup 1.0000x reference)
//
#include <hip/hip_runtime.h>
#include <cstddef>

#define BB   8
#define TT   1024
#define DDIM 128
#define HH   8
#define DHH  16
#define FF   256
#define BT   (BB * TT)   // 8192

typedef unsigned short u16;
typedef __attribute__((ext_vector_type(8))) short short8;
typedef __attribute__((ext_vector_type(4))) float f32x4;

__device__ __forceinline__ u16 bf(float x) {
  unsigned u = __builtin_bit_cast(unsigned, x);
  u += 0x7fffu + ((u >> 16) & 1u);   // RTN-even
  return (u16)(u >> 16);
}
__device__ __forceinline__ u16 bft(float x) {           // truncate (P in [0,1])
  return (u16)(__builtin_bit_cast(unsigned, x) >> 16);
}
__device__ __forceinline__ float gelu_f(float x) {
  const float t = x * (0.79788456f + 0.03567740814f * x * x);
  return x / (1.0f + __expf(-2.0f * t));
}

// ---------------------------------------------------------------------------
// QKV tail: As holds 32 normalized bf16 rows; run 3 GEMM passes producing
// q (bf16), k (bf16), vT (transposed: vT[(b*8+h)*16+c][s]). Proven pattern.
// ---------------------------------------------------------------------------
__device__ __forceinline__ void qkv_tail(
    const u16* __restrict__ Wq, const u16* __restrict__ Wk, const u16* __restrict__ Wv,
    u16* __restrict__ q_out, u16* __restrict__ k_out, u16* __restrict__ vT_out,
    int m0, u16 (*As)[136], u16 (*Bs)[136]) {
  const int tid = threadIdx.x;
  const int w = tid >> 6, lane = tid & 63, l15 = lane & 15, quad = lane >> 4;
  const int wr = w & 1, wc = w >> 1;
  const u16* Ws[3] = {Wq, Wk, Wv};
  #pragma unroll
  for (int wi = 0; wi < 3; ++wi) {
    #pragma unroll
    for (int t = tid; t < 2048; t += 256) {
      const int r = t >> 4, g8 = (t & 15) << 3;
      *(short8*)&Bs[r][g8] = *(const short8*)(Ws[wi] + (size_t)r * 128 + g8);
    }
    __syncthreads();
    f32x4 acc[4];
    #pragma unroll
    for (int j = 0; j < 4; ++j) acc[j] = {0.f, 0.f, 0.f, 0.f};
    #pragma unroll
    for (int ks = 0; ks < 4; ++ks) {
      const short8 ar = *(const short8*)&As[wr * 16 + l15][ks * 32 + quad * 8];
      #pragma unroll
      for (int j = 0; j < 4; ++j) {
        const short8 br = *(const short8*)&Bs[wc * 64 + j * 16 + l15][ks * 32 + quad * 8];
        acc[j] = __builtin_amdgcn_mfma_f32_16x16x32_bf16(ar, br, acc[j], 0, 0, 0);
      }
    }
    if (wi == 2) {
      const int m_base = m0 + wr * 16 + quad * 4;
      const int bb_ = m_base >> 10, s = m_base & 1023;
      #pragma unroll
      for (int j = 0; j < 4; ++j) {
        const int n = wc * 64 + j * 16 + l15;
        const int h = n >> 4, c = n & 15;
        ushort4 o;
        o.x = bf(acc[j][0]); o.y = bf(acc[j][1]);
        o.z = bf(acc[j][2]); o.w = bf(acc[j][3]);
        *(ushort4*)(vT_out + (((size_t)(bb_ * 8 + h) * 16 + c) << 10) + s) = o;
      }
    } else {
      u16* out = (wi == 0) ? q_out : k_out;
      #pragma unroll
      for (int j = 0; j < 4; ++j) {
        const int n = wc * 64 + j * 16 + l15;
        #pragma unroll
        for (int reg = 0; reg < 4; ++reg) {
          const int m = m0 + wr * 16 + quad * 4 + reg;
          out[(size_t)m * 128 + n] = bf(acc[j][reg]);
        }
      }
    }
    __syncthreads();   // Bs free for next pass
  }
}

// ---------------------------------------------------------------------------
// Weight prep: fp32 (K,N) -> bf16 (N,K)  (transpose + convert), 18 matrices.
// ---------------------------------------------------------------------------
struct PrepP { const float* W; u16* Wt; int K; int N; };
struct PrepArgs { PrepP p[18]; };

__global__ __launch_bounds__(256) void prep_k(PrepArgs a) {
  const PrepP pp = a.p[blockIdx.z];
  const int n0 = blockIdx.x * 64, k0 = blockIdx.y * 64;
  if (n0 >= pp.N || k0 >= pp.K) return;
  __shared__ float tile[64][65];
  const int tid = threadIdx.x;
  #pragma unroll
  for (int t = tid; t < 1024; t += 256) {
    const int kk = t >> 4, nn4 = (t & 15) << 2;
    float4 v = *(const float4*)(pp.W + (size_t)(k0 + kk) * pp.N + n0 + nn4);
    tile[nn4 + 0][kk] = v.x; tile[nn4 + 1][kk] = v.y;
    tile[nn4 + 2][kk] = v.z; tile[nn4 + 3][kk] = v.w;
  }
  __syncthreads();
  #pragma unroll
  for (int t = tid; t < 1024; t += 256) {
    const int nn = t >> 4, kk4 = (t & 15) << 2;
    ushort4 o;
    o.x = bf(tile[nn][kk4 + 0]); o.y = bf(tile[nn][kk4 + 1]);
    o.z = bf(tile[nn][kk4 + 2]); o.w = bf(tile[nn][kk4 + 3]);
    *(ushort4*)(pp.Wt + (size_t)(n0 + nn) * pp.K + k0 + kk4) = o;
  }
}

// ---------------------------------------------------------------------------
// lnqkv_k: layer-0 LN1 (fp32 in, fragment-layout loads) -> As, then QKV tail.
// ---------------------------------------------------------------------------
struct LnqkvP { const float* in; const float* g; const float* b;
                const u16* Wq; const u16* Wk; const u16* Wv;
                u16* q_out; u16* k_out; u16* vT_out; };
struct LnqkvArgs { LnqkvP p[2]; };

__global__ __launch_bounds__(256) void lnqkv_k(LnqkvArgs a) {
  const LnqkvP pp = a.p[blockIdx.y];
  const int m0 = blockIdx.x * 32;
  __shared__ __align__(16) u16 As[32][136];
  __shared__ __align__(16) u16 Bs[128][136];
  __shared__ float2 stats[32][2];
  const int tid  = threadIdx.x;
  const int w    = tid >> 6;
  const int lane = tid & 63;
  const int l15  = lane & 15;
  const int quad = lane >> 4;
  const int wr = w & 1, wc = w >> 1;

  float xv[4][4];
  #pragma unroll
  for (int j = 0; j < 4; ++j) {
    const int n = wc * 64 + j * 16 + l15;
    #pragma unroll
    for (int reg = 0; reg < 4; ++reg) {
      const int m = m0 + wr * 16 + quad * 4 + reg;
      xv[j][reg] = pp.in[(size_t)m * 128 + n];
    }
  }
  #pragma unroll
  for (int reg = 0; reg < 4; ++reg) {
    float s = 0.f, q = 0.f;
    #pragma unroll
    for (int j = 0; j < 4; ++j) { const float v = xv[j][reg]; s += v; q += v * v; }
    #pragma unroll
    for (int off = 8; off >= 1; off >>= 1) {
      s += __shfl_xor(s, off, 16);
      q += __shfl_xor(q, off, 16);
    }
    if (l15 == 0) stats[wr * 16 + quad * 4 + reg][wc] = make_float2(s, q);
  }
  __syncthreads();
  #pragma unroll
  for (int reg = 0; reg < 4; ++reg) {
    const int mloc = wr * 16 + quad * 4 + reg;
    const float2 s0 = stats[mloc][0], s1 = stats[mloc][1];
    const float mean = (s0.x + s1.x) * (1.0f / 128.f);
    const float var  = (s0.y + s1.y) * (1.0f / 128.f) - mean * mean;
    const float r    = rsqrtf(var + 1e-5f);
    #pragma unroll
    for (int j = 0; j < 4; ++j) {
      const int n = wc * 64 + j * 16 + l15;
      As[mloc][n] = bf((xv[j][reg] - mean) * r * pp.g[n] + pp.b[n]);
    }
  }
  qkv_tail(pp.Wq, pp.Wk, pp.Wv, pp.q_out, pp.k_out, pp.vT_out, m0, As, Bs);
}

// ---------------------------------------------------------------------------
// Fused Wo + residual + LN2 + FFN1 + gelu + FFN2 + residual
// [+ next-layer LN1 + next-layer QKV tail when ln==1].
// ---------------------------------------------------------------------------
struct WofnP { const u16* A; const u16* WoT; const float* bo; const float* res;
               const float* g2; const float* b2l;
               const u16* W1t; const float* b1;
               const u16* W2t; const float* b2;
               float* outF;
               const float* gn; const float* bn;                 // next LN1
               const u16* nWq; const u16* nWk; const u16* nWv;   // next QKV
               u16* q_out; u16* k_out; u16* vT_out; };
struct WofnArgs { WofnP p[2]; int ln; };

__global__ __launch_bounds__(256) void wofn_k(WofnArgs a) {
  const WofnP pp = a.p[blockIdx.y];
  const int m0 = blockIdx.x * 32;
  __shared__ __align__(16) u16 As[32][136];
  __shared__ __align__(16) u16 Bs[128][136];
  __shared__ __align__(16) u16 Hs[32][264];
  __shared__ float2 stats[32][2];
  const int tid  = threadIdx.x;
  const int w    = tid >> 6;
  const int lane = tid & 63;
  const int l15  = lane & 15;
  const int quad = lane >> 4;
  const int wr = w & 1, wc = w >> 1;

  // ---- stage ob + WoT, Wo GEMM ----
  #pragma unroll
  for (int t = tid; t < 512; t += 256) {
    const int r = t >> 4, g8 = (t & 15) << 3;
    *(short8*)&As[r][g8] = *(const short8*)(pp.A + (size_t)(m0 + r) * 128 + g8);
  }
  #pragma unroll
  for (int t = tid; t < 2048; t += 256) {
    const int r = t >> 4, g8 = (t & 15) << 3;
    *(short8*)&Bs[r][g8] = *(const short8*)(pp.WoT + (size_t)r * 128 + g8);
  }
  __syncthreads();
  f32x4 acc[4];
  #pragma unroll
  for (int j = 0; j < 4; ++j) acc[j] = {0.f, 0.f, 0.f, 0.f};
  #pragma unroll
  for (int ks = 0; ks < 4; ++ks) {
    const short8 ar = *(const short8*)&As[wr * 16 + l15][ks * 32 + quad * 8];
    #pragma unroll
    for (int j = 0; j < 4; ++j) {
      const short8 br = *(const short8*)&Bs[wc * 64 + j * 16 + l15][ks * 32 + quad * 8];
      acc[j] = __builtin_amdgcn_mfma_f32_16x16x32_bf16(ar, br, acc[j], 0, 0, 0);
    }
  }

  // ---- x = Wo-out + bias + residual (registers) ----
  float xv[4][4];
  #pragma unroll
  for (int j = 0; j < 4; ++j) {
    const int n = wc * 64 + j * 16 + l15;
    const float bias_v = pp.bo[n];
    #pragma unroll
    for (int reg = 0; reg < 4; ++reg) {
      const int m = m0 + wr * 16 + quad * 4 + reg;
      xv[j][reg] = acc[j][reg] + bias_v + pp.res[(size_t)m * 128 + n];
    }
  }

  // ---- LN2 -> normalized bf16 into As ----
  #pragma unroll
  for (int reg = 0; reg < 4; ++reg) {
    float s = 0.f, q = 0.f;
    #pragma unroll
    for (int j = 0; j < 4; ++j) { const float v = xv[j][reg]; s += v; q += v * v; }
    #pragma unroll
    for (int off = 8; off >= 1; off >>= 1) {
      s += __shfl_xor(s, off, 16);
      q += __shfl_xor(q, off, 16);
    }
    if (l15 == 0) stats[wr * 16 + quad * 4 + reg][wc] = make_float2(s, q);
  }
  __syncthreads();
  #pragma unroll
  for (int reg = 0; reg < 4; ++reg) {
    const int mloc = wr * 16 + quad * 4 + reg;
    const float2 s0 = stats[mloc][0], s1 = stats[mloc][1];
    const float mean = (s0.x + s1.x) * (1.0f / 128.f);
    const float var  = (s0.y + s1.y) * (1.0f / 128.f) - mean * mean;
    const float r    = rsqrtf(var + 1e-5f);
    #pragma unroll
    for (int j = 0; j < 4; ++j) {
      const int n = wc * 64 + j * 16 + l15;
      As[mloc][n] = bf((xv[j][reg] - mean) * r * pp.g2[n] + pp.b2l[n]);
    }
  }
  __syncthreads();   // As (LN2 out) visible; Bs free

  // ---- FFN1: h = gelu(xn@W1+b1) in LDS, two 128-col halves ----
  for (int nh = 0; nh < 2; ++nh) {
    #pragma unroll
    for (int t = tid; t < 2048; t += 256) {
      const int r = t >> 4, g8 = (t & 15) << 3;
      *(short8*)&Bs[r][g8] = *(const short8*)(pp.W1t + (size_t)(nh * 128 + r) * 128 + g8);
    }
    __syncthreads();
    f32x4 a1[4];
    #pragma unroll
    for (int j = 0; j < 4; ++j) a1[j] = {0.f, 0.f, 0.f, 0.f};
    #pragma unroll
    for (int ks = 0; ks < 4; ++ks) {
      const short8 ar = *(const short8*)&As[wr * 16 + l15][ks * 32 + quad * 8];
      #pragma unroll
      for (int j = 0; j < 4; ++j) {
        const short8 br = *(const short8*)&Bs[wc * 64 + j * 16 + l15][ks * 32 + quad * 8];
        a1[j] = __builtin_amdgcn_mfma_f32_16x16x32_bf16(ar, br, a1[j], 0, 0, 0);
      }
    }
    #pragma unroll
    for (int j = 0; j < 4; ++j) {
      const int n = wc * 64 + j * 16 + l15;
      const float bias_v = pp.b1[nh * 128 + n];
      #pragma unroll
      for (int reg = 0; reg < 4; ++reg) {
        const int mloc = wr * 16 + quad * 4 + reg;
        Hs[mloc][nh * 128 + n] = bf(gelu_f(a1[j][reg] + bias_v));
      }
    }
    __syncthreads();
  }

  // ---- FFN2: out = h@W2 + b2 + x (registers), two K-halves ----
  f32x4 a2[4];
  #pragma unroll
  for (int j = 0; j < 4; ++j) a2[j] = {0.f, 0.f, 0.f, 0.f};
  for (int kh = 0; kh < 2; ++kh) {
    #pragma unroll
    for (int t = tid; t < 2048; t += 256) {
      const int r = t >> 4, g8 = (t & 15) << 3;
      *(short8*)&Bs[r][g8] = *(const short8*)(pp.W2t + (size_t)r * 256 + kh * 128 + g8);
    }
    __syncthreads();
    #pragma unroll
    for (int ks = 0; ks < 4; ++ks) {
      const short8 ar = *(const short8*)&Hs[wr * 16 + l15][kh * 128 + ks * 32 + quad * 8];
      #pragma unroll
      for (int j = 0; j < 4; ++j) {
        const short8 br = *(const short8*)&Bs[wc * 64 + j * 16 + l15][ks * 32 + quad * 8];
        a2[j] = __builtin_amdgcn_mfma_f32_16x16x32_bf16(ar, br, a2[j], 0, 0, 0);
      }
    }
    __syncthreads();
  }

  // ---- epilogue: + b2 + x (reg), fp32 out ----
  #pragma unroll
  for (int j = 0; j < 4; ++j) {
    const int n = wc * 64 + j * 16 + l15;
    const float bias_v = pp.b2[n];
    #pragma unroll
    for (int reg = 0; reg < 4; ++reg) {
      const int m = m0 + wr * 16 + quad * 4 + reg;
      const float v = a2[j][reg] + bias_v + xv[j][reg];
      xv[j][reg] = v;
      pp.outF[(size_t)m * 128 + n] = v;
    }
  }
  if (!a.ln) return;

  // ---- next-layer LN1 -> As, then next-layer QKV tail ----
  #pragma unroll
  for (int reg = 0; reg < 4; ++reg) {
    float s = 0.f, q = 0.f;
    #pragma unroll
    for (int j = 0; j < 4; ++j) { const float v = xv[j][reg]; s += v; q += v * v; }
    #pragma unroll
    for (int off = 8; off >= 1; off >>= 1) {
      s += __shfl_xor(s, off, 16);
      q += __shfl_xor(q, off, 16);
    }
    if (l15 == 0) stats[wr * 16 + quad * 4 + reg][wc] = make_float2(s, q);
  }
  __syncthreads();
  #pragma unroll
  for (int reg = 0; reg < 4; ++reg) {
    const int mloc = wr * 16 + quad * 4 + reg;
    const float2 s0 = stats[mloc][0], s1 = stats[mloc][1];
    const float mean = (s0.x + s1.x) * (1.0f / 128.f);
    const float var  = (s0.y + s1.y) * (1.0f / 128.f) - mean * mean;
    const float r    = rsqrtf(var + 1e-5f);
    #pragma unroll
    for (int j = 0; j < 4; ++j) {
      const int n = wc * 64 + j * 16 + l15;
      As[mloc][n] = bf((xv[j][reg] - mean) * r * pp.gn[n] + pp.bn[n]);
    }
  }
  qkv_tail(pp.nWq, pp.nWk, pp.nWv, pp.q_out, pp.k_out, pp.vT_out, m0, As, Bs);
}

// ---------------------------------------------------------------------------
// MFMA flash attention, 128 q-rows / block (wave owns 32 = 2 row-tiles).
// S^T orientation (mfma(kb, qa)): lane's regs = 4 consecutive keys at one
// query => packed b64 P-writes, scalar denominators. kb loaded from LDS once,
// reused for both row-tiles. V pre-transposed => b128-copy staging. 64-key dbuf.
// ---------------------------------------------------------------------------
__global__ __launch_bounds__(256) void attn_k(const u16* __restrict__ qx,
                                              const u16* __restrict__ kx,
                                              const u16* __restrict__ qy,
                                              const u16* __restrict__ ky,
                                              const u16* __restrict__ vtx,
                                              const u16* __restrict__ vty,
                                              u16* __restrict__ o1,
                                              u16* __restrict__ o2) {
  const int t0 = blockIdx.x * 128;
  const int bh = blockIdx.y;
  const int b = bh >> 3, h = bh & 7;
  const size_t base = (size_t)b * TT * DDIM + h * DHH;

  __shared__ __align__(16) u16 Ks[2][64][40];
  __shared__ __align__(16) u16 Vt[2][32][72];
  __shared__ __align__(16) u16 Ps[128][72];

  const int tid  = threadIdx.x;
  const int w    = tid >> 6;
  const int lane = tid & 63;
  const int l15  = lane & 15;
  const int quad = lane >> 4;

  const u16* qp = (quad < 2) ? qx : qy;
  const int dq = (quad & 1) * 8;
  short8 qa[2];
  #pragma unroll
  for (int u = 0; u < 2; ++u)
    qa[u] = *(const short8*)(qp + base + (size_t)(t0 + w * 32 + u * 16 + l15) * DDIM + dq);

  f32x4 Of[2][2];
  #pragma unroll
  for (int u = 0; u < 2; ++u) { Of[u][0] = {0,0,0,0}; Of[u][1] = {0,0,0,0}; }
  float l_i[2] = {0.f, 0.f};

  const int ks_s = tid >> 2, ks_c = tid & 3;
  const u16* ks_p = (ks_c < 2) ? kx : ky;
  const int ks_d8 = (ks_c & 1) * 8;
  const int ks_col = (ks_c < 2 ? 0 : 16) + ks_d8;

  const int vs_c = tid >> 3;
  const int vs_s8 = (tid & 7) * 8;
  const u16* vs_row = (vs_c < 16) ? (vtx + (((size_t)bh * 16 + vs_c) << 10))
                                  : (vty + (((size_t)bh * 16 + (vs_c - 16)) << 10));

  #define STAGE(kt, buf)                                                          \
    do {                                                                          \
      const int s0_ = (kt) * 64;                                                  \
      *(short8*)&Ks[buf][ks_s][ks_col] =                                          \
          *(const short8*)(ks_p + base + (size_t)(s0_ + ks_s) * DDIM + ks_d8);    \
      *(short8*)&Vt[buf][vs_c][vs_s8] = *(const short8*)(vs_row + s0_ + vs_s8);   \
    } while (0)

  STAGE(0, 0);

  for (int kt = 0; kt < TT / 64; ++kt) {
    const int buf = kt & 1;
    __syncthreads();
    if (kt + 1 < TT / 64) STAGE(kt + 1, buf ^ 1);

    // K fragments once, reused for both row-tiles
    short8 kb[4];
    #pragma unroll
    for (int t = 0; t < 4; ++t)
      kb[t] = *(const short8*)&Ks[buf][t * 16 + l15][quad * 8];

    #pragma unroll
    for (int u = 0; u < 2; ++u) {
      f32x4 Sf[4];
      #pragma unroll
      for (int t = 0; t < 4; ++t) {
        f32x4 z = {0.f, 0.f, 0.f, 0.f};
        Sf[t] = __builtin_amdgcn_mfma_f32_16x16x32_bf16(kb[t], qa[u], z, 0, 0, 0);
      }
      #pragma unroll
      for (int t = 0; t < 4; ++t) {
        const float p0 = exp2f(Sf[t][0] * 0.18033688011112042f);
        const float p1 = exp2f(Sf[t][1] * 0.18033688011112042f);
        const float p2 = exp2f(Sf[t][2] * 0.18033688011112042f);
        const float p3 = exp2f(Sf[t][3] * 0.18033688011112042f);
        l_i[u] += p0 + p1 + p2 + p3;
        ushort4 pk;
        pk.x = bft(p0); pk.y = bft(p1); pk.z = bft(p2); pk.w = bft(p3);
        *(ushort4*)&Ps[w * 32 + u * 16 + l15][t * 16 + quad * 4] = pk;
      }
    }

    #pragma unroll
    for (int sh = 0; sh < 2; ++sh) {
      short8 vb0 = *(const short8*)&Vt[buf][l15][sh * 32 + quad * 8];
      short8 vb1 = *(const short8*)&Vt[buf][16 + l15][sh * 32 + quad * 8];
      #pragma unroll
      for (int u = 0; u < 2; ++u) {
        short8 pa = *(const short8*)&Ps[w * 32 + u * 16 + l15][sh * 32 + quad * 8];
        Of[u][0] = __builtin_amdgcn_mfma_f32_16x16x32_bf16(pa, vb0, Of[u][0], 0, 0, 0);
        Of[u][1] = __builtin_amdgcn_mfma_f32_16x16x32_bf16(pa, vb1, Of[u][1], 0, 0, 0);
      }
    }
  }
  #undef STAGE

  #pragma unroll
  for (int u = 0; u < 2; ++u) {
    float l = l_i[u];
    l += __shfl_xor(l, 16);
    l += __shfl_xor(l, 32);
    #pragma unroll
    for (int reg = 0; reg < 4; ++reg) {
      const float lq = __shfl(l, quad * 4 + reg, 16);
      const float inv = 1.0f / lq;
      const size_t r = base + (size_t)(t0 + w * 32 + u * 16 + quad * 4 + reg) * DDIM + l15;
      o1[r] = bf(Of[u][0][reg] * inv);
      o2[r] = bf(Of[u][1][reg] * inv);
    }
  }
}

// ---------------------------------------------------------------------------
extern "C" void kernel_launch(void* const* d_in, const int* in_sizes, int n_in,
                              void* d_out, int out_size, void* d_ws, size_t ws_size,
                              hipStream_t stream) {
  const float* x_in  = (const float*)d_in[0];
  const float* y_in  = (const float*)d_in[1];
  const float* Wq    = (const float*)d_in[2];
  const float* Wk    = (const float*)d_in[3];
  const float* Wv    = (const float*)d_in[4];
  const float* Wox   = (const float*)d_in[5];
  const float* box   = (const float*)d_in[6];
  const float* Woy   = (const float*)d_in[7];
  const float* boy   = (const float*)d_in[8];
  const float* ln1xg = (const float*)d_in[9];
  const float* ln1xb = (const float*)d_in[10];
  const float* ln1yg = (const float*)d_in[11];
  const float* ln1yb = (const float*)d_in[12];
  const float* ln2xg = (const float*)d_in[13];
  const float* ln2xb = (const float*)d_in[14];
  const float* ln2yg = (const float*)d_in[15];
  const float* ln2yb = (const float*)d_in[16];
  const float* fxw1  = (const float*)d_in[17];
  const float* fxb1  = (const float*)d_in[18];
  const float* fxw2  = (const float*)d_in[19];
  const float* fxb2  = (const float*)d_in[20];
  const float* fyw1  = (const float*)d_in[21];
  const float* fyb1  = (const float*)d_in[22];
  const float* fyw2  = (const float*)d_in[23];
  const float* fyb2  = (const float*)d_in[24];

  const size_t S = (size_t)BT * DDIM;  // 1,048,576 elems
  float* X = (float*)d_out;
  float* Y = X + S;

  char* wsb = (char*)d_ws;
  auto carve = [&](size_t bytes) { char* p = wsb; wsb += (bytes + 255) & ~(size_t)255; return p; };
  u16* qx  = (u16*)carve(S * 2);
  u16* kx  = (u16*)carve(S * 2);
  u16* qy  = (u16*)carve(S * 2);
  u16* ky  = (u16*)carve(S * 2);
  u16* vxT = (u16*)carve(S * 2);   // vT[(b*8+h)*16+c][s]
  u16* vyT = (u16*)carve(S * 2);
  u16* ob1 = (u16*)carve(S * 2);
  u16* ob2 = (u16*)carve(S * 2);
  u16* WqT[2], *WkT[2], *WvT[2], *WoxT[2], *WoyT[2];
  u16* f1xT[2], *f1yT[2], *f2xT[2], *f2yT[2];
  for (int l = 0; l < 2; ++l) {
    WqT[l]  = (u16*)carve(16384 * 2);
    WkT[l]  = (u16*)carve(16384 * 2);
    WvT[l]  = (u16*)carve(16384 * 2);
    WoxT[l] = (u16*)carve(16384 * 2);
    WoyT[l] = (u16*)carve(16384 * 2);
    f1xT[l] = (u16*)carve(32768 * 2);
    f1yT[l] = (u16*)carve(32768 * 2);
    f2xT[l] = (u16*)carve(32768 * 2);
    f2yT[l] = (u16*)carve(32768 * 2);
  }

  // weight transpose+convert (all layers, one kernel)
  {
    PrepArgs a;
    int idx = 0;
    for (int l = 0; l < 2; ++l) {
      a.p[idx++] = {Wq  + (size_t)l * 16384, WqT[l],  128, 128};
      a.p[idx++] = {Wk  + (size_t)l * 16384, WkT[l],  128, 128};
      a.p[idx++] = {Wv  + (size_t)l * 16384, WvT[l],  128, 128};
      a.p[idx++] = {Wox + (size_t)l * 16384, WoxT[l], 128, 128};
      a.p[idx++] = {Woy + (size_t)l * 16384, WoyT[l], 128, 128};
      a.p[idx++] = {fxw1 + (size_t)l * 32768, f1xT[l], 128, 256};
      a.p[idx++] = {fyw1 + (size_t)l * 32768, f1yT[l], 128, 256};
      a.p[idx++] = {fxw2 + (size_t)l * 32768, f2xT[l], 256, 128};
      a.p[idx++] = {fyw2 + (size_t)l * 32768, f2yT[l], 256, 128};
    }
    prep_k<<<dim3(4, 4, 18), 256, 0, stream>>>(a);
  }

  // layer-0 LN1 + QKV (fused)
  {
    LnqkvArgs a;
    a.p[0] = {x_in, ln1xg, ln1xb, WqT[0], WkT[0], WvT[0], qy, kx, vxT};
    a.p[1] = {y_in, ln1yg, ln1yb, WqT[0], WkT[0], WvT[0], qx, ky, vyT};
    lnqkv_k<<<dim3(BT / 32, 2), 256, 0, stream>>>(a);
  }

  for (int l = 0; l < 2; ++l) {
    const size_t bo  = (size_t)l * DDIM;
    const size_t fbo = (size_t)l * FF;

    // fused attention (128 q-rows per block)
    attn_k<<<dim3(TT / 128, BB * HH), 256, 0, stream>>>(qx, kx, qy, ky, vxT, vyT, ob1, ob2);

    // fused Wo + res + LN2 + FFN (+ next-layer LN1 + QKV for l==0)
    {
      const float* resx = (l == 0) ? x_in : X;
      const float* resy = (l == 0) ? y_in : Y;
      WofnArgs a = {}; a.ln = (l == 0) ? 1 : 0;
      a.p[0] = {ob1, WoxT[l], box + bo, resx, ln2xg + bo, ln2xb + bo,
                f1xT[l], fxb1 + fbo, f2xT[l], fxb2 + bo, X,
                (l == 0) ? ln1xg + DDIM : nullptr, (l == 0) ? ln1xb + DDIM : nullptr,
                (l == 0) ? WqT[1] : nullptr, (l == 0) ? WkT[1] : nullptr,
                (l == 0) ? WvT[1] : nullptr,
                (l == 0) ? qy : nullptr, (l == 0) ? kx : nullptr,
                (l == 0) ? vxT : nullptr};
      a.p[1] = {ob2, WoyT[l], boy + bo, resy, ln2yg + bo, ln2yb + bo,
                f1yT[l], fyb1 + fbo, f2yT[l], fyb2 + bo, Y,
                (l == 0) ? ln1yg + DDIM : nullptr, (l == 0) ? ln1yb + DDIM : nullptr,
                (l == 0) ? WqT[1] : nullptr, (l == 0) ? WkT[1] : nullptr,
                (l == 0) ? WvT[1] : nullptr,
                (l == 0) ? qx : nullptr, (l == 0) ? ky : nullptr,
                (l == 0) ? vyT : nullptr};
      wofn_k<<<dim3(BT / 32, 2), 256, 0, stream>>>(a);
    }
  }
}

// Round 15
// 219.380 us; speedup vs baseline: 1.0326x; 1.0326x over previous
//
#include <hip/hip_runtime.h>
#include <cstddef>

#define BB   8
#define TT   1024
#define DDIM 128
#define HH   8
#define DHH  16
#define FF   256
#define BT   (BB * TT)   // 8192

typedef unsigned short u16;
typedef __attribute__((ext_vector_type(8))) short short8;
typedef __attribute__((ext_vector_type(4))) float f32x4;

__device__ __forceinline__ u16 bf(float x) {
  unsigned u = __builtin_bit_cast(unsigned, x);
  u += 0x7fffu + ((u >> 16) & 1u);   // RTN-even
  return (u16)(u >> 16);
}
__device__ __forceinline__ u16 bft(float x) {           // truncate (P in [0,1])
  return (u16)(__builtin_bit_cast(unsigned, x) >> 16);
}
__device__ __forceinline__ float gelu_f(float x) {
  const float t = x * (0.79788456f + 0.03567740814f * x * x);
  return x / (1.0f + __expf(-2.0f * t));
}

// ---------------------------------------------------------------------------
// QKV tail: As holds 32 normalized bf16 rows; run 3 GEMM passes producing
// q (bf16), k (bf16), vT (transposed: vT[(b*8+h)*16+c][s]). Proven pattern.
// ---------------------------------------------------------------------------
__device__ __forceinline__ void qkv_tail(
    const u16* __restrict__ Wq, const u16* __restrict__ Wk, const u16* __restrict__ Wv,
    u16* __restrict__ q_out, u16* __restrict__ k_out, u16* __restrict__ vT_out,
    int m0, u16 (*As)[136], u16 (*Bs)[136]) {
  const int tid = threadIdx.x;
  const int w = tid >> 6, lane = tid & 63, l15 = lane & 15, quad = lane >> 4;
  const int wr = w & 1, wc = w >> 1;
  const u16* Ws[3] = {Wq, Wk, Wv};
  #pragma unroll
  for (int wi = 0; wi < 3; ++wi) {
    #pragma unroll
    for (int t = tid; t < 2048; t += 256) {
      const int r = t >> 4, g8 = (t & 15) << 3;
      *(short8*)&Bs[r][g8] = *(const short8*)(Ws[wi] + (size_t)r * 128 + g8);
    }
    __syncthreads();
    f32x4 acc[4];
    #pragma unroll
    for (int j = 0; j < 4; ++j) acc[j] = {0.f, 0.f, 0.f, 0.f};
    #pragma unroll
    for (int ks = 0; ks < 4; ++ks) {
      const short8 ar = *(const short8*)&As[wr * 16 + l15][ks * 32 + quad * 8];
      #pragma unroll
      for (int j = 0; j < 4; ++j) {
        const short8 br = *(const short8*)&Bs[wc * 64 + j * 16 + l15][ks * 32 + quad * 8];
        acc[j] = __builtin_amdgcn_mfma_f32_16x16x32_bf16(ar, br, acc[j], 0, 0, 0);
      }
    }
    if (wi == 2) {
      const int m_base = m0 + wr * 16 + quad * 4;
      const int bb_ = m_base >> 10, s = m_base & 1023;
      #pragma unroll
      for (int j = 0; j < 4; ++j) {
        const int n = wc * 64 + j * 16 + l15;
        const int h = n >> 4, c = n & 15;
        ushort4 o;
        o.x = bf(acc[j][0]); o.y = bf(acc[j][1]);
        o.z = bf(acc[j][2]); o.w = bf(acc[j][3]);
        *(ushort4*)(vT_out + (((size_t)(bb_ * 8 + h) * 16 + c) << 10) + s) = o;
      }
    } else {
      u16* out = (wi == 0) ? q_out : k_out;
      #pragma unroll
      for (int j = 0; j < 4; ++j) {
        const int n = wc * 64 + j * 16 + l15;
        #pragma unroll
        for (int reg = 0; reg < 4; ++reg) {
          const int m = m0 + wr * 16 + quad * 4 + reg;
          out[(size_t)m * 128 + n] = bf(acc[j][reg]);
        }
      }
    }
    __syncthreads();   // Bs free for next pass
  }
}

// ---------------------------------------------------------------------------
// Weight prep: fp32 (K,N) -> bf16 (N,K)  (transpose + convert), 18 matrices.
// ---------------------------------------------------------------------------
struct PrepP { const float* W; u16* Wt; int K; int N; };
struct PrepArgs { PrepP p[18]; };

__global__ __launch_bounds__(256) void prep_k(PrepArgs a) {
  const PrepP pp = a.p[blockIdx.z];
  const int n0 = blockIdx.x * 64, k0 = blockIdx.y * 64;
  if (n0 >= pp.N || k0 >= pp.K) return;
  __shared__ float tile[64][65];
  const int tid = threadIdx.x;
  #pragma unroll
  for (int t = tid; t < 1024; t += 256) {
    const int kk = t >> 4, nn4 = (t & 15) << 2;
    float4 v = *(const float4*)(pp.W + (size_t)(k0 + kk) * pp.N + n0 + nn4);
    tile[nn4 + 0][kk] = v.x; tile[nn4 + 1][kk] = v.y;
    tile[nn4 + 2][kk] = v.z; tile[nn4 + 3][kk] = v.w;
  }
  __syncthreads();
  #pragma unroll
  for (int t = tid; t < 1024; t += 256) {
    const int nn = t >> 4, kk4 = (t & 15) << 2;
    ushort4 o;
    o.x = bf(tile[nn][kk4 + 0]); o.y = bf(tile[nn][kk4 + 1]);
    o.z = bf(tile[nn][kk4 + 2]); o.w = bf(tile[nn][kk4 + 3]);
    *(ushort4*)(pp.Wt + (size_t)(n0 + nn) * pp.K + k0 + kk4) = o;
  }
}

// ---------------------------------------------------------------------------
// lnqkv_k: layer-0 LN1 (fp32 in, fragment-layout loads) -> As, then QKV tail.
// ---------------------------------------------------------------------------
struct LnqkvP { const float* in; const float* g; const float* b;
                const u16* Wq; const u16* Wk; const u16* Wv;
                u16* q_out; u16* k_out; u16* vT_out; };
struct LnqkvArgs { LnqkvP p[2]; };

__global__ __launch_bounds__(256) void lnqkv_k(LnqkvArgs a) {
  const LnqkvP pp = a.p[blockIdx.y];
  const int m0 = blockIdx.x * 32;
  __shared__ __align__(16) u16 As[32][136];
  __shared__ __align__(16) u16 Bs[128][136];
  __shared__ float2 stats[32][2];
  const int tid  = threadIdx.x;
  const int w    = tid >> 6;
  const int lane = tid & 63;
  const int l15  = lane & 15;
  const int quad = lane >> 4;
  const int wr = w & 1, wc = w >> 1;

  float xv[4][4];
  #pragma unroll
  for (int j = 0; j < 4; ++j) {
    const int n = wc * 64 + j * 16 + l15;
    #pragma unroll
    for (int reg = 0; reg < 4; ++reg) {
      const int m = m0 + wr * 16 + quad * 4 + reg;
      xv[j][reg] = pp.in[(size_t)m * 128 + n];
    }
  }
  #pragma unroll
  for (int reg = 0; reg < 4; ++reg) {
    float s = 0.f, q = 0.f;
    #pragma unroll
    for (int j = 0; j < 4; ++j) { const float v = xv[j][reg]; s += v; q += v * v; }
    #pragma unroll
    for (int off = 8; off >= 1; off >>= 1) {
      s += __shfl_xor(s, off, 16);
      q += __shfl_xor(q, off, 16);
    }
    if (l15 == 0) stats[wr * 16 + quad * 4 + reg][wc] = make_float2(s, q);
  }
  __syncthreads();
  #pragma unroll
  for (int reg = 0; reg < 4; ++reg) {
    const int mloc = wr * 16 + quad * 4 + reg;
    const float2 s0 = stats[mloc][0], s1 = stats[mloc][1];
    const float mean = (s0.x + s1.x) * (1.0f / 128.f);
    const float var  = (s0.y + s1.y) * (1.0f / 128.f) - mean * mean;
    const float r    = rsqrtf(var + 1e-5f);
    #pragma unroll
    for (int j = 0; j < 4; ++j) {
      const int n = wc * 64 + j * 16 + l15;
      As[mloc][n] = bf((xv[j][reg] - mean) * r * pp.g[n] + pp.b[n]);
    }
  }
  qkv_tail(pp.Wq, pp.Wk, pp.Wv, pp.q_out, pp.k_out, pp.vT_out, m0, As, Bs);
}

// ---------------------------------------------------------------------------
// Fused Wo + residual + LN2 + FFN1 + gelu + FFN2 + residual
// [+ next-layer LN1 + next-layer QKV tail when ln==1].
// ---------------------------------------------------------------------------
struct WofnP { const u16* A; const u16* WoT; const float* bo; const float* res;
               const float* g2; const float* b2l;
               const u16* W1t; const float* b1;
               const u16* W2t; const float* b2;
               float* outF;
               const float* gn; const float* bn;                 // next LN1
               const u16* nWq; const u16* nWk; const u16* nWv;   // next QKV
               u16* q_out; u16* k_out; u16* vT_out; };
struct WofnArgs { WofnP p[2]; int ln; };

__global__ __launch_bounds__(256) void wofn_k(WofnArgs a) {
  const WofnP pp = a.p[blockIdx.y];
  const int m0 = blockIdx.x * 32;
  __shared__ __align__(16) u16 As[32][136];
  __shared__ __align__(16) u16 Bs[128][136];
  __shared__ __align__(16) u16 Hs[32][264];
  __shared__ float2 stats[32][2];
  const int tid  = threadIdx.x;
  const int w    = tid >> 6;
  const int lane = tid & 63;
  const int l15  = lane & 15;
  const int quad = lane >> 4;
  const int wr = w & 1, wc = w >> 1;

  // ---- stage ob + WoT, Wo GEMM ----
  #pragma unroll
  for (int t = tid; t < 512; t += 256) {
    const int r = t >> 4, g8 = (t & 15) << 3;
    *(short8*)&As[r][g8] = *(const short8*)(pp.A + (size_t)(m0 + r) * 128 + g8);
  }
  #pragma unroll
  for (int t = tid; t < 2048; t += 256) {
    const int r = t >> 4, g8 = (t & 15) << 3;
    *(short8*)&Bs[r][g8] = *(const short8*)(pp.WoT + (size_t)r * 128 + g8);
  }
  __syncthreads();
  f32x4 acc[4];
  #pragma unroll
  for (int j = 0; j < 4; ++j) acc[j] = {0.f, 0.f, 0.f, 0.f};
  #pragma unroll
  for (int ks = 0; ks < 4; ++ks) {
    const short8 ar = *(const short8*)&As[wr * 16 + l15][ks * 32 + quad * 8];
    #pragma unroll
    for (int j = 0; j < 4; ++j) {
      const short8 br = *(const short8*)&Bs[wc * 64 + j * 16 + l15][ks * 32 + quad * 8];
      acc[j] = __builtin_amdgcn_mfma_f32_16x16x32_bf16(ar, br, acc[j], 0, 0, 0);
    }
  }

  // ---- x = Wo-out + bias + residual (registers) ----
  float xv[4][4];
  #pragma unroll
  for (int j = 0; j < 4; ++j) {
    const int n = wc * 64 + j * 16 + l15;
    const float bias_v = pp.bo[n];
    #pragma unroll
    for (int reg = 0; reg < 4; ++reg) {
      const int m = m0 + wr * 16 + quad * 4 + reg;
      xv[j][reg] = acc[j][reg] + bias_v + pp.res[(size_t)m * 128 + n];
    }
  }

  // ---- LN2 -> normalized bf16 into As ----
  #pragma unroll
  for (int reg = 0; reg < 4; ++reg) {
    float s = 0.f, q = 0.f;
    #pragma unroll
    for (int j = 0; j < 4; ++j) { const float v = xv[j][reg]; s += v; q += v * v; }
    #pragma unroll
    for (int off = 8; off >= 1; off >>= 1) {
      s += __shfl_xor(s, off, 16);
      q += __shfl_xor(q, off, 16);
    }
    if (l15 == 0) stats[wr * 16 + quad * 4 + reg][wc] = make_float2(s, q);
  }
  __syncthreads();
  #pragma unroll
  for (int reg = 0; reg < 4; ++reg) {
    const int mloc = wr * 16 + quad * 4 + reg;
    const float2 s0 = stats[mloc][0], s1 = stats[mloc][1];
    const float mean = (s0.x + s1.x) * (1.0f / 128.f);
    const float var  = (s0.y + s1.y) * (1.0f / 128.f) - mean * mean;
    const float r    = rsqrtf(var + 1e-5f);
    #pragma unroll
    for (int j = 0; j < 4; ++j) {
      const int n = wc * 64 + j * 16 + l15;
      As[mloc][n] = bf((xv[j][reg] - mean) * r * pp.g2[n] + pp.b2l[n]);
    }
  }
  __syncthreads();   // As (LN2 out) visible; Bs free

  // ---- FFN1: h = gelu(xn@W1+b1) in LDS, two 128-col halves ----
  for (int nh = 0; nh < 2; ++nh) {
    #pragma unroll
    for (int t = tid; t < 2048; t += 256) {
      const int r = t >> 4, g8 = (t & 15) << 3;
      *(short8*)&Bs[r][g8] = *(const short8*)(pp.W1t + (size_t)(nh * 128 + r) * 128 + g8);
    }
    __syncthreads();
    f32x4 a1[4];
    #pragma unroll
    for (int j = 0; j < 4; ++j) a1[j] = {0.f, 0.f, 0.f, 0.f};
    #pragma unroll
    for (int ks = 0; ks < 4; ++ks) {
      const short8 ar = *(const short8*)&As[wr * 16 + l15][ks * 32 + quad * 8];
      #pragma unroll
      for (int j = 0; j < 4; ++j) {
        const short8 br = *(const short8*)&Bs[wc * 64 + j * 16 + l15][ks * 32 + quad * 8];
        a1[j] = __builtin_amdgcn_mfma_f32_16x16x32_bf16(ar, br, a1[j], 0, 0, 0);
      }
    }
    #pragma unroll
    for (int j = 0; j < 4; ++j) {
      const int n = wc * 64 + j * 16 + l15;
      const float bias_v = pp.b1[nh * 128 + n];
      #pragma unroll
      for (int reg = 0; reg < 4; ++reg) {
        const int mloc = wr * 16 + quad * 4 + reg;
        Hs[mloc][nh * 128 + n] = bf(gelu_f(a1[j][reg] + bias_v));
      }
    }
    __syncthreads();
  }

  // ---- FFN2: out = h@W2 + b2 + x (registers), two K-halves ----
  f32x4 a2[4];
  #pragma unroll
  for (int j = 0; j < 4; ++j) a2[j] = {0.f, 0.f, 0.f, 0.f};
  for (int kh = 0; kh < 2; ++kh) {
    #pragma unroll
    for (int t = tid; t < 2048; t += 256) {
      const int r = t >> 4, g8 = (t & 15) << 3;
      *(short8*)&Bs[r][g8] = *(const short8*)(pp.W2t + (size_t)r * 256 + kh * 128 + g8);
    }
    __syncthreads();
    #pragma unroll
    for (int ks = 0; ks < 4; ++ks) {
      const short8 ar = *(const short8*)&Hs[wr * 16 + l15][kh * 128 + ks * 32 + quad * 8];
      #pragma unroll
      for (int j = 0; j < 4; ++j) {
        const short8 br = *(const short8*)&Bs[wc * 64 + j * 16 + l15][ks * 32 + quad * 8];
        a2[j] = __builtin_amdgcn_mfma_f32_16x16x32_bf16(ar, br, a2[j], 0, 0, 0);
      }
    }
    __syncthreads();
  }

  // ---- epilogue: + b2 + x (reg), fp32 out ----
  #pragma unroll
  for (int j = 0; j < 4; ++j) {
    const int n = wc * 64 + j * 16 + l15;
    const float bias_v = pp.b2[n];
    #pragma unroll
    for (int reg = 0; reg < 4; ++reg) {
      const int m = m0 + wr * 16 + quad * 4 + reg;
      const float v = a2[j][reg] + bias_v + xv[j][reg];
      xv[j][reg] = v;
      pp.outF[(size_t)m * 128 + n] = v;
    }
  }
  if (!a.ln) return;

  // ---- next-layer LN1 -> As, then next-layer QKV tail ----
  #pragma unroll
  for (int reg = 0; reg < 4; ++reg) {
    float s = 0.f, q = 0.f;
    #pragma unroll
    for (int j = 0; j < 4; ++j) { const float v = xv[j][reg]; s += v; q += v * v; }
    #pragma unroll
    for (int off = 8; off >= 1; off >>= 1) {
      s += __shfl_xor(s, off, 16);
      q += __shfl_xor(q, off, 16);
    }
    if (l15 == 0) stats[wr * 16 + quad * 4 + reg][wc] = make_float2(s, q);
  }
  __syncthreads();
  #pragma unroll
  for (int reg = 0; reg < 4; ++reg) {
    const int mloc = wr * 16 + quad * 4 + reg;
    const float2 s0 = stats[mloc][0], s1 = stats[mloc][1];
    const float mean = (s0.x + s1.x) * (1.0f / 128.f);
    const float var  = (s0.y + s1.y) * (1.0f / 128.f) - mean * mean;
    const float r    = rsqrtf(var + 1e-5f);
    #pragma unroll
    for (int j = 0; j < 4; ++j) {
      const int n = wc * 64 + j * 16 + l15;
      As[mloc][n] = bf((xv[j][reg] - mean) * r * pp.gn[n] + pp.bn[n]);
    }
  }
  qkv_tail(pp.nWq, pp.nWk, pp.nWv, pp.q_out, pp.k_out, pp.vT_out, m0, As, Bs);
}

// ---------------------------------------------------------------------------
// MFMA flash attention, 64 q-rows / block (R13 shape: 1024 blocks = 4/CU).
// S^T orientation (mfma(kb, qa)): packed b64 P-writes, scalar denominator.
// V pre-transposed => b128-copy staging. Register-pipelined K/V prefetch:
// globals for tile k+1 load during tile k-1's compute; after the barrier only
// the (already-resident) register->LDS writes remain.
// ---------------------------------------------------------------------------
__global__ __launch_bounds__(256) void attn_k(const u16* __restrict__ qx,
                                              const u16* __restrict__ kx,
                                              const u16* __restrict__ qy,
                                              const u16* __restrict__ ky,
                                              const u16* __restrict__ vtx,
                                              const u16* __restrict__ vty,
                                              u16* __restrict__ o1,
                                              u16* __restrict__ o2) {
  const int t0 = blockIdx.x * 64;
  const int bh = blockIdx.y;
  const int b = bh >> 3, h = bh & 7;
  const size_t base = (size_t)b * TT * DDIM + h * DHH;

  __shared__ __align__(16) u16 Ks[2][64][40];
  __shared__ __align__(16) u16 Vt[2][32][72];
  __shared__ __align__(16) u16 Ps[64][72];

  const int tid  = threadIdx.x;
  const int w    = tid >> 6;
  const int lane = tid & 63;
  const int l15  = lane & 15;
  const int quad = lane >> 4;

  const u16* qp = (quad < 2) ? qx : qy;
  const int dq = (quad & 1) * 8;
  const short8 qa = *(const short8*)(qp + base + (size_t)(t0 + w * 16 + l15) * DDIM + dq);

  f32x4 Of0 = {0.f, 0.f, 0.f, 0.f};
  f32x4 Of1 = {0.f, 0.f, 0.f, 0.f};
  float l_i = 0.f;

  const int ks_s = tid >> 2, ks_c = tid & 3;
  const u16* ks_p = (ks_c < 2) ? kx : ky;
  const int ks_d8 = (ks_c & 1) * 8;
  const int ks_col = (ks_c < 2 ? 0 : 16) + ks_d8;
  const u16* ks_src = ks_p + base + (size_t)ks_s * DDIM + ks_d8;  // + s0*DDIM

  const int vs_c = tid >> 3;
  const int vs_s8 = (tid & 7) * 8;
  const u16* vs_row = (vs_c < 16) ? (vtx + (((size_t)bh * 16 + vs_c) << 10))
                                  : (vty + (((size_t)bh * 16 + (vs_c - 16)) << 10));

  // tile 0: straight to LDS
  *(short8*)&Ks[0][ks_s][ks_col] = *(const short8*)(ks_src);
  *(short8*)&Vt[0][vs_c][vs_s8]  = *(const short8*)(vs_row + vs_s8);

  // prefetch tile 1 into registers
  short8 kreg = *(const short8*)(ks_src + (size_t)64 * DDIM);
  short8 vreg = *(const short8*)(vs_row + 64 + vs_s8);

  for (int kt = 0; kt < TT / 64; ++kt) {
    const int buf = kt & 1;
    __syncthreads();
    if (kt + 1 < TT / 64) {
      // write prefetched tile k+1 (registers already resident)
      *(short8*)&Ks[buf ^ 1][ks_s][ks_col] = kreg;
      *(short8*)&Vt[buf ^ 1][vs_c][vs_s8]  = vreg;
      if (kt + 2 < TT / 64) {
        const int s2 = (kt + 2) * 64;
        kreg = *(const short8*)(ks_src + (size_t)s2 * DDIM);
        vreg = *(const short8*)(vs_row + s2 + vs_s8);
      }
    }

    f32x4 Sf[4];
    #pragma unroll
    for (int t = 0; t < 4; ++t) {
      short8 kb = *(const short8*)&Ks[buf][t * 16 + l15][quad * 8];
      f32x4 z = {0.f, 0.f, 0.f, 0.f};
      Sf[t] = __builtin_amdgcn_mfma_f32_16x16x32_bf16(kb, qa, z, 0, 0, 0);
    }

    #pragma unroll
    for (int t = 0; t < 4; ++t) {
      const float p0 = exp2f(Sf[t][0] * 0.18033688011112042f);
      const float p1 = exp2f(Sf[t][1] * 0.18033688011112042f);
      const float p2 = exp2f(Sf[t][2] * 0.18033688011112042f);
      const float p3 = exp2f(Sf[t][3] * 0.18033688011112042f);
      l_i += p0 + p1 + p2 + p3;
      ushort4 pk;
      pk.x = bft(p0); pk.y = bft(p1); pk.z = bft(p2); pk.w = bft(p3);
      *(ushort4*)&Ps[w * 16 + l15][t * 16 + quad * 4] = pk;
    }

    #pragma unroll
    for (int sh = 0; sh < 2; ++sh) {
      short8 pa  = *(const short8*)&Ps[w * 16 + l15][sh * 32 + quad * 8];
      short8 vb0 = *(const short8*)&Vt[buf][l15][sh * 32 + quad * 8];
      short8 vb1 = *(const short8*)&Vt[buf][16 + l15][sh * 32 + quad * 8];
      Of0 = __builtin_amdgcn_mfma_f32_16x16x32_bf16(pa, vb0, Of0, 0, 0, 0);
      Of1 = __builtin_amdgcn_mfma_f32_16x16x32_bf16(pa, vb1, Of1, 0, 0, 0);
    }
  }

  l_i += __shfl_xor(l_i, 16);
  l_i += __shfl_xor(l_i, 32);
  #pragma unroll
  for (int reg = 0; reg < 4; ++reg) {
    const float lq = __shfl(l_i, quad * 4 + reg, 16);
    const float inv = 1.0f / lq;
    const size_t r = base + (size_t)(t0 + w * 16 + quad * 4 + reg) * DDIM + l15;
    o1[r] = bf(Of0[reg] * inv);
    o2[r] = bf(Of1[reg] * inv);
  }
}

// ---------------------------------------------------------------------------
extern "C" void kernel_launch(void* const* d_in, const int* in_sizes, int n_in,
                              void* d_out, int out_size, void* d_ws, size_t ws_size,
                              hipStream_t stream) {
  const float* x_in  = (const float*)d_in[0];
  const float* y_in  = (const float*)d_in[1];
  const float* Wq    = (const float*)d_in[2];
  const float* Wk    = (const float*)d_in[3];
  const float* Wv    = (const float*)d_in[4];
  const float* Wox   = (const float*)d_in[5];
  const float* box   = (const float*)d_in[6];
  const float* Woy   = (const float*)d_in[7];
  const float* boy   = (const float*)d_in[8];
  const float* ln1xg = (const float*)d_in[9];
  const float* ln1xb = (const float*)d_in[10];
  const float* ln1yg = (const float*)d_in[11];
  const float* ln1yb = (const float*)d_in[12];
  const float* ln2xg = (const float*)d_in[13];
  const float* ln2xb = (const float*)d_in[14];
  const float* ln2yg = (const float*)d_in[15];
  const float* ln2yb = (const float*)d_in[16];
  const float* fxw1  = (const float*)d_in[17];
  const float* fxb1  = (const float*)d_in[18];
  const float* fxw2  = (const float*)d_in[19];
  const float* fxb2  = (const float*)d_in[20];
  const float* fyw1  = (const float*)d_in[21];
  const float* fyb1  = (const float*)d_in[22];
  const float* fyw2  = (const float*)d_in[23];
  const float* fyb2  = (const float*)d_in[24];

  const size_t S = (size_t)BT * DDIM;  // 1,048,576 elems
  float* X = (float*)d_out;
  float* Y = X + S;

  char* wsb = (char*)d_ws;
  auto carve = [&](size_t bytes) { char* p = wsb; wsb += (bytes + 255) & ~(size_t)255; return p; };
  u16* qx  = (u16*)carve(S * 2);
  u16* kx  = (u16*)carve(S * 2);
  u16* qy  = (u16*)carve(S * 2);
  u16* ky  = (u16*)carve(S * 2);
  u16* vxT = (u16*)carve(S * 2);   // vT[(b*8+h)*16+c][s]
  u16* vyT = (u16*)carve(S * 2);
  u16* ob1 = (u16*)carve(S * 2);
  u16* ob2 = (u16*)carve(S * 2);
  u16* WqT[2], *WkT[2], *WvT[2], *WoxT[2], *WoyT[2];
  u16* f1xT[2], *f1yT[2], *f2xT[2], *f2yT[2];
  for (int l = 0; l < 2; ++l) {
    WqT[l]  = (u16*)carve(16384 * 2);
    WkT[l]  = (u16*)carve(16384 * 2);
    WvT[l]  = (u16*)carve(16384 * 2);
    WoxT[l] = (u16*)carve(16384 * 2);
    WoyT[l] = (u16*)carve(16384 * 2);
    f1xT[l] = (u16*)carve(32768 * 2);
    f1yT[l] = (u16*)carve(32768 * 2);
    f2xT[l] = (u16*)carve(32768 * 2);
    f2yT[l] = (u16*)carve(32768 * 2);
  }

  // weight transpose+convert (all layers, one kernel)
  {
    PrepArgs a;
    int idx = 0;
    for (int l = 0; l < 2; ++l) {
      a.p[idx++] = {Wq  + (size_t)l * 16384, WqT[l],  128, 128};
      a.p[idx++] = {Wk  + (size_t)l * 16384, WkT[l],  128, 128};
      a.p[idx++] = {Wv  + (size_t)l * 16384, WvT[l],  128, 128};
      a.p[idx++] = {Wox + (size_t)l * 16384, WoxT[l], 128, 128};
      a.p[idx++] = {Woy + (size_t)l * 16384, WoyT[l], 128, 128};
      a.p[idx++] = {fxw1 + (size_t)l * 32768, f1xT[l], 128, 256};
      a.p[idx++] = {fyw1 + (size_t)l * 32768, f1yT[l], 128, 256};
      a.p[idx++] = {fxw2 + (size_t)l * 32768, f2xT[l], 256, 128};
      a.p[idx++] = {fyw2 + (size_t)l * 32768, f2yT[l], 256, 128};
    }
    prep_k<<<dim3(4, 4, 18), 256, 0, stream>>>(a);
  }

  // layer-0 LN1 + QKV (fused)
  {
    LnqkvArgs a;
    a.p[0] = {x_in, ln1xg, ln1xb, WqT[0], WkT[0], WvT[0], qy, kx, vxT};
    a.p[1] = {y_in, ln1yg, ln1yb, WqT[0], WkT[0], WvT[0], qx, ky, vyT};
    lnqkv_k<<<dim3(BT / 32, 2), 256, 0, stream>>>(a);
  }

  for (int l = 0; l < 2; ++l) {
    const size_t bo  = (size_t)l * DDIM;
    const size_t fbo = (size_t)l * FF;

    // fused attention (64 q-rows per block, register-pipelined staging)
    attn_k<<<dim3(TT / 64, BB * HH), 256, 0, stream>>>(qx, kx, qy, ky, vxT, vyT, ob1, ob2);

    // fused Wo + res + LN2 + FFN (+ next-layer LN1 + QKV for l==0)
    {
      const float* resx = (l == 0) ? x_in : X;
      const float* resy = (l == 0) ? y_in : Y;
      WofnArgs a = {}; a.ln = (l == 0) ? 1 : 0;
      a.p[0] = {ob1, WoxT[l], box + bo, resx, ln2xg + bo, ln2xb + bo,
                f1xT[l], fxb1 + fbo, f2xT[l], fxb2 + bo, X,
                (l == 0) ? ln1xg + DDIM : nullptr, (l == 0) ? ln1xb + DDIM : nullptr,
                (l == 0) ? WqT[1] : nullptr, (l == 0) ? WkT[1] : nullptr,
                (l == 0) ? WvT[1] : nullptr,
                (l == 0) ? qy : nullptr, (l == 0) ? kx : nullptr,
                (l == 0) ? vxT : nullptr};
      a.p[1] = {ob2, WoyT[l], boy + bo, resy, ln2yg + bo, ln2yb + bo,
                f1yT[l], fyb1 + fbo, f2yT[l], fyb2 + bo, Y,
                (l == 0) ? ln1yg + DDIM : nullptr, (l == 0) ? ln1yb + DDIM : nullptr,
                (l == 0) ? WqT[1] : nullptr, (l == 0) ? WkT[1] : nullptr,
                (l == 0) ? WvT[1] : nullptr,
                (l == 0) ? qx : nullptr, (l == 0) ? ky : nullptr,
                (l == 0) ? vyT : nullptr};
      wofn_k<<<dim3(BT / 32, 2), 256, 0, stream>>>(a);
    }
  }
}